// Round 1
// baseline (2156.411 us; speedup 1.0000x reference)
//
#include <hip/hip_runtime.h>
#include <math.h>

// Problem constants
namespace {
constexpr int B = 2, C = 16, D = 16, H = 128, W = 128;
constexpr int HW   = H * W;        // 16384
constexpr int DHW  = D * HW;       // 262144
constexpr int CDHW = C * DHW;      // 4194304
constexpr float EPSBN = 1e-5f;

// workspace offsets (in floats); total 37,748,736 floats = 151 MB
constexpr long long OFF_X1  = 0;
constexpr long long OFF_X2  = 8388608;
constexpr long long OFF_Q   = 16777216;  // (B,D,2,H,W)
constexpr long long OFF_K   = 17825792;  // (B,D,2,H,W)
constexpr long long OFF_V   = 18874368;  // (B,D,16,H,W)
constexpr long long OFF_KT  = 27262976;  // (B,D,2,W,H)
constexpr long long OFF_VT  = 28311552;  // (B,D,16,W,H)
constexpr long long OFF_MST = 36700160;  // (B,D,2,W,H): m, 1/s
}

// ---------------------------------------------------------------------------
// K1: conv_pre (1x3x3, pad 0,1,1) + BN + ReLU.   grid(64, D, B), block 256.
// ---------------------------------------------------------------------------
__global__ __launch_bounds__(256) void k_conv_pre(
    const float* __restrict__ x, const float* __restrict__ wp,
    const float* __restrict__ bg, const float* __restrict__ bb,
    const float* __restrict__ bm, const float* __restrict__ bv,
    float* __restrict__ out)
{
  __shared__ float xs[16][18][18];
  __shared__ float sc[16], bi[16];
  const int tid = threadIdx.x;
  const int tile = blockIdx.x;              // 0..63
  const int d = blockIdx.y, b = blockIdx.z;
  const int h0 = (tile >> 3) * 16, w0 = (tile & 7) * 16;

  if (tid < 16) {
    float s = bg[tid] * rsqrtf(bv[tid] + EPSBN);
    sc[tid] = s;
    bi[tid] = bb[tid] - bm[tid] * s;
  }
  const float* xb = x + (long long)b * CDHW + (long long)d * HW;
  for (int idx = tid; idx < 16 * 324; idx += 256) {
    int cin = idx / 324, rem = idx - cin * 324;
    int ph = rem / 18, pw = rem - ph * 18;
    int gh = h0 - 1 + ph, gw = w0 - 1 + pw;
    float v = 0.f;
    if (gh >= 0 && gh < H && gw >= 0 && gw < W)
      v = xb[(long long)cin * DHW + gh * W + gw];
    xs[cin][ph][pw] = v;
  }
  __syncthreads();

  const int ty = tid >> 4, tx = tid & 15;
  float acc[16];
  #pragma unroll
  for (int co = 0; co < 16; ++co) acc[co] = 0.f;

  for (int cin = 0; cin < 16; ++cin) {
    #pragma unroll
    for (int kh = 0; kh < 3; ++kh) {
      #pragma unroll
      for (int kw = 0; kw < 3; ++kw) {
        float xv = xs[cin][ty + kh][tx + kw];
        const int wi = cin * 9 + kh * 3 + kw;   // uniform -> s_load weights
        #pragma unroll
        for (int co = 0; co < 16; ++co)
          acc[co] = fmaf(xv, wp[co * 144 + wi], acc[co]);
      }
    }
  }
  float* ob = out + (long long)b * CDHW + (long long)d * HW + (h0 + ty) * W + (w0 + tx);
  #pragma unroll
  for (int co = 0; co < 16; ++co)
    ob[(long long)co * DHW] = fmaxf(fmaf(acc[co], sc[co], bi[co]), 0.f);
}

// ---------------------------------------------------------------------------
// K2: q,k,v projections + transposed copies.  grid(64, D, B), block 256.
// ---------------------------------------------------------------------------
__global__ __launch_bounds__(256) void k_qkv(
    const float* __restrict__ xin, const float* __restrict__ wq,
    const float* __restrict__ wk, const float* __restrict__ wv,
    float* __restrict__ Qp, float* __restrict__ Kp, float* __restrict__ Vp,
    float* __restrict__ KTp, float* __restrict__ VTp)
{
  const int tid = threadIdx.x;
  const int tile = blockIdx.x, d = blockIdx.y, b = blockIdx.z;
  const int h0 = (tile >> 3) * 16, w0 = (tile & 7) * 16;
  const int ty = tid >> 4, tx = tid & 15;
  const int h = h0 + ty, w = w0 + tx;

  const float* xb = xin + (long long)b * CDHW + (long long)d * HW + h * W + w;
  float xv[16];
  #pragma unroll
  for (int c = 0; c < 16; ++c) xv[c] = xb[(long long)c * DHW];

  float q0 = 0, q1 = 0, k0 = 0, k1 = 0, v[16];
  #pragma unroll
  for (int c = 0; c < 16; ++c) {
    q0 = fmaf(wq[c], xv[c], q0);
    q1 = fmaf(wq[16 + c], xv[c], q1);
    k0 = fmaf(wk[c], xv[c], k0);
    k1 = fmaf(wk[16 + c], xv[c], k1);
  }
  #pragma unroll
  for (int o = 0; o < 16; ++o) {
    float a = 0;
    #pragma unroll
    for (int c = 0; c < 16; ++c) a = fmaf(wv[o * 16 + c], xv[c], a);
    v[o] = a;
  }

  const int sl = b * 16 + d;
  const int hw = h * W + w;
  Qp[(long long)(sl * 2 + 0) * HW + hw] = q0;
  Qp[(long long)(sl * 2 + 1) * HW + hw] = q1;
  Kp[(long long)(sl * 2 + 0) * HW + hw] = k0;
  Kp[(long long)(sl * 2 + 1) * HW + hw] = k1;
  #pragma unroll
  for (int o = 0; o < 16; ++o) Vp[(long long)(sl * 16 + o) * HW + hw] = v[o];

  __shared__ float lsk[2][16][17];
  __shared__ float lsv[16][16][17];
  lsk[0][ty][tx] = k0; lsk[1][ty][tx] = k1;
  #pragma unroll
  for (int o = 0; o < 16; ++o) lsv[o][ty][tx] = v[o];
  __syncthreads();

  const int wh = (w0 + ty) * 128 + (h0 + tx);   // (w, h) coords transposed
  KTp[(long long)(sl * 2 + 0) * HW + wh] = lsk[0][tx][ty];
  KTp[(long long)(sl * 2 + 1) * HW + wh] = lsk[1][tx][ty];
  #pragma unroll
  for (int o = 0; o < 16; ++o) VTp[(long long)(sl * 16 + o) * HW + wh] = lsv[o][tx][ty];
}

// ---------------------------------------------------------------------------
// K3: softmax stats (eH with diag mask + eW) + oW term.
// block 128 = 4 h-rows x 32 lanes, each thread owns 4 w's. grid(32, D, B).
// writes out = xin + gamma*oW ; writes MST (m, 1/s) in W-major.
// ---------------------------------------------------------------------------
__global__ __launch_bounds__(128, 1) void k_att_row(
    const float* __restrict__ xin, float* __restrict__ out,
    const float* __restrict__ Qp, const float* __restrict__ Kp,
    const float* __restrict__ Vp, float* __restrict__ MSTp,
    const float* __restrict__ gp)
{
  __shared__ float krow[4][2][128];
  __shared__ __align__(16) float vrow[4][128][20];  // [hi][v][c], pad 16->20
  const int tid = threadIdx.x;
  const int h0 = blockIdx.x * 4, d = blockIdx.y, b = blockIdx.z;
  const int sl = b * 16 + d;
  const long long base2 = (long long)(sl * 2) * HW;
  const long long baseV = (long long)(sl * 16) * HW;
  const int hi = tid >> 5, wt = tid & 31;
  const int h = h0 + hi;

  // cooperative loads (lane index = fastest dim -> coalesced)
  for (int kk = 0; kk < 8; ++kk) {            // 4*2*128 / 128
    int o = kk & 1, r2 = kk >> 1;
    krow[r2][o][tid] = Kp[base2 + (long long)o * HW + (h0 + r2) * W + tid];
  }
  for (int kk = 0; kk < 64; ++kk) {           // 4*128*16 / 128
    int hi2 = kk & 3, c2 = kk >> 2;
    vrow[hi2][tid][c2] = Vp[baseV + (long long)c2 * HW + (h0 + hi2) * W + tid];
  }
  __syncthreads();

  const float* K0 = Kp + base2;
  const float* K1 = Kp + base2 + HW;
  int wr[4]; float q0[4], q1[4];
  #pragma unroll
  for (int r = 0; r < 4; ++r) {
    wr[r] = wt + 32 * r;
    q0[r] = Qp[base2 + h * W + wr[r]];
    q1[r] = Qp[base2 + HW + h * W + wr[r]];
  }

  // pass 1: max over eH (masked diag) and eW
  float m[4] = {-3e38f, -3e38f, -3e38f, -3e38f};
  for (int j = 0; j < 128; ++j) {
    #pragma unroll
    for (int r = 0; r < 4; ++r) {
      float e = fmaf(q0[r], K0[j * W + wr[r]], q1[r] * K1[j * W + wr[r]]);
      e = (j == h) ? -3e38f : e;
      m[r] = fmaxf(m[r], e);
    }
  }
  for (int v = 0; v < 128; ++v) {
    float kv0 = krow[hi][0][v], kv1 = krow[hi][1][v];
    #pragma unroll
    for (int r = 0; r < 4; ++r)
      m[r] = fmaxf(m[r], fmaf(q0[r], kv0, q1[r] * kv1));
  }

  // pass 2: sum of exp; fuse oW accumulation on the eW half
  float s[4] = {0.f, 0.f, 0.f, 0.f};
  float acc[4][16];
  #pragma unroll
  for (int r = 0; r < 4; ++r)
    #pragma unroll
    for (int c = 0; c < 16; ++c) acc[r][c] = 0.f;

  for (int j = 0; j < 128; ++j) {
    #pragma unroll
    for (int r = 0; r < 4; ++r) {
      float e = fmaf(q0[r], K0[j * W + wr[r]], q1[r] * K1[j * W + wr[r]]);
      float a = (j == h) ? 0.f : __expf(e - m[r]);
      s[r] += a;
    }
  }
  for (int v = 0; v < 128; ++v) {
    float kv0 = krow[hi][0][v], kv1 = krow[hi][1][v];
    const float4 V0 = *(const float4*)&vrow[hi][v][0];
    const float4 V1 = *(const float4*)&vrow[hi][v][4];
    const float4 V2 = *(const float4*)&vrow[hi][v][8];
    const float4 V3 = *(const float4*)&vrow[hi][v][12];
    #pragma unroll
    for (int r = 0; r < 4; ++r) {
      float e = fmaf(q0[r], kv0, q1[r] * kv1);
      float a = __expf(e - m[r]);
      s[r] += a;
      acc[r][0]  = fmaf(a, V0.x, acc[r][0]);  acc[r][1]  = fmaf(a, V0.y, acc[r][1]);
      acc[r][2]  = fmaf(a, V0.z, acc[r][2]);  acc[r][3]  = fmaf(a, V0.w, acc[r][3]);
      acc[r][4]  = fmaf(a, V1.x, acc[r][4]);  acc[r][5]  = fmaf(a, V1.y, acc[r][5]);
      acc[r][6]  = fmaf(a, V1.z, acc[r][6]);  acc[r][7]  = fmaf(a, V1.w, acc[r][7]);
      acc[r][8]  = fmaf(a, V2.x, acc[r][8]);  acc[r][9]  = fmaf(a, V2.y, acc[r][9]);
      acc[r][10] = fmaf(a, V2.z, acc[r][10]); acc[r][11] = fmaf(a, V2.w, acc[r][11]);
      acc[r][12] = fmaf(a, V3.x, acc[r][12]); acc[r][13] = fmaf(a, V3.y, acc[r][13]);
      acc[r][14] = fmaf(a, V3.z, acc[r][14]); acc[r][15] = fmaf(a, V3.w, acc[r][15]);
    }
  }

  const float gamma = gp[0];
  const long long ob = (long long)b * CDHW + (long long)d * HW + h * W;
  #pragma unroll
  for (int r = 0; r < 4; ++r) {
    float inv = 1.f / s[r];
    MSTp[base2 + wr[r] * 128 + h] = m[r];
    MSTp[base2 + HW + wr[r] * 128 + h] = inv;
    float gi = gamma * inv;
    #pragma unroll
    for (int c = 0; c < 16; ++c) {
      long long idx = ob + (long long)c * DHW + wr[r];
      out[idx] = xin[idx] + gi * acc[r][c];
    }
  }
}

// ---------------------------------------------------------------------------
// K4: oH term, accumulated into out.
// block 128 = 4 w-cols x 32 lanes, each thread owns 4 h's. grid(32, D, B).
// ---------------------------------------------------------------------------
__global__ __launch_bounds__(128, 1) void k_att_col(
    float* __restrict__ out, const float* __restrict__ Qp,
    const float* __restrict__ KTp, const float* __restrict__ VTp,
    const float* __restrict__ MSTp, const float* __restrict__ gp)
{
  __shared__ float kc[4][2][128];
  __shared__ __align__(16) float vc[4][128][20];   // [wi][j][c]
  __shared__ float mmr[4][128], iir[4][128];
  const int tid = threadIdx.x;
  const int w0 = blockIdx.x * 4, d = blockIdx.y, b = blockIdx.z;
  const int sl = b * 16 + d;
  const long long base2 = (long long)(sl * 2) * HW;
  const long long baseV = (long long)(sl * 16) * HW;
  const int wi = tid >> 5, hi = tid & 31;
  const int w = w0 + wi;

  for (int kk = 0; kk < 8; ++kk) {
    int o = kk & 1, r2 = kk >> 1;
    kc[r2][o][tid] = KTp[base2 + (long long)o * HW + (w0 + r2) * 128 + tid];
  }
  for (int kk = 0; kk < 64; ++kk) {
    int wi2 = kk & 3, c2 = kk >> 2;
    vc[wi2][tid][c2] = VTp[baseV + (long long)c2 * HW + (w0 + wi2) * 128 + tid];
  }
  for (int kk = 0; kk < 4; ++kk) {
    mmr[kk][tid] = MSTp[base2 + (w0 + kk) * 128 + tid];
    iir[kk][tid] = MSTp[base2 + HW + (w0 + kk) * 128 + tid];
  }
  __syncthreads();

  int hr[4]; float q0[4], q1[4], m[4], is[4];
  #pragma unroll
  for (int r = 0; r < 4; ++r) {
    hr[r] = hi + 32 * r;
    q0[r] = Qp[base2 + hr[r] * W + w];
    q1[r] = Qp[base2 + HW + hr[r] * W + w];
    m[r]  = mmr[wi][hr[r]];
    is[r] = iir[wi][hr[r]];
  }
  float acc[4][16];
  #pragma unroll
  for (int r = 0; r < 4; ++r)
    #pragma unroll
    for (int c = 0; c < 16; ++c) acc[r][c] = 0.f;

  for (int j = 0; j < 128; ++j) {
    float k0 = kc[wi][0][j], k1 = kc[wi][1][j];
    const float4 V0 = *(const float4*)&vc[wi][j][0];
    const float4 V1 = *(const float4*)&vc[wi][j][4];
    const float4 V2 = *(const float4*)&vc[wi][j][8];
    const float4 V3 = *(const float4*)&vc[wi][j][12];
    #pragma unroll
    for (int r = 0; r < 4; ++r) {
      float e = fmaf(q0[r], k0, q1[r] * k1);
      float a = (j == hr[r]) ? 0.f : __expf(e - m[r]);
      acc[r][0]  = fmaf(a, V0.x, acc[r][0]);  acc[r][1]  = fmaf(a, V0.y, acc[r][1]);
      acc[r][2]  = fmaf(a, V0.z, acc[r][2]);  acc[r][3]  = fmaf(a, V0.w, acc[r][3]);
      acc[r][4]  = fmaf(a, V1.x, acc[r][4]);  acc[r][5]  = fmaf(a, V1.y, acc[r][5]);
      acc[r][6]  = fmaf(a, V1.z, acc[r][6]);  acc[r][7]  = fmaf(a, V1.w, acc[r][7]);
      acc[r][8]  = fmaf(a, V2.x, acc[r][8]);  acc[r][9]  = fmaf(a, V2.y, acc[r][9]);
      acc[r][10] = fmaf(a, V2.z, acc[r][10]); acc[r][11] = fmaf(a, V2.w, acc[r][11]);
      acc[r][12] = fmaf(a, V3.x, acc[r][12]); acc[r][13] = fmaf(a, V3.y, acc[r][13]);
      acc[r][14] = fmaf(a, V3.z, acc[r][14]); acc[r][15] = fmaf(a, V3.w, acc[r][15]);
    }
  }

  const float gamma = gp[0];
  const long long ob = (long long)b * CDHW + (long long)d * HW;
  #pragma unroll
  for (int r = 0; r < 4; ++r) {
    float gi = gamma * is[r];
    #pragma unroll
    for (int c = 0; c < 16; ++c)
      out[ob + (long long)c * DHW + hr[r] * W + w] += gi * acc[r][c];
  }
}

// ---------------------------------------------------------------------------
// K5: conv_gate (3x3x3, pad 1, 16->64ch) + BN + activations + SRU scan over D,
// fused (no gates buffer). block 256 = 16x16 tile; grid(64, C, B); one thread
// per (b,c,h,w) carrying Ct across d. Weights via wave-uniform s_loads.
// ---------------------------------------------------------------------------
__global__ __launch_bounds__(256) void k_gate_scan(
    const float* __restrict__ x, const float* __restrict__ wg,
    const float* __restrict__ bg, const float* __restrict__ bb,
    const float* __restrict__ bm, const float* __restrict__ bv,
    float* __restrict__ out)
{
  const int tid = threadIdx.x;
  const int tile = blockIdx.x;
  const int c = blockIdx.y, b = blockIdx.z;
  const int h0 = (tile >> 3) * 16, w0 = (tile & 7) * 16;
  const int ty = tid >> 4, tx = tid & 15;
  const int h = h0 + ty, w = w0 + tx;

  float sc[4], bi[4];
  #pragma unroll
  for (int g = 0; g < 4; ++g) {
    int ch = c + 16 * g;
    float s = bg[ch] * rsqrtf(bv[ch] + EPSBN);
    sc[g] = s;
    bi[g] = bb[ch] - bm[ch] * s;
  }
  const float* xb = x + (long long)b * CDHW;
  const int wb0 = (c) * 432, wb1 = (c + 16) * 432, wb2 = (c + 32) * 432, wb3 = (c + 48) * 432;

  float Ct = 0.f;
  float* ob = out + (long long)b * CDHW + (long long)c * DHW + h * W + w;

  for (int d = 0; d < D; ++d) {
    float a0 = 0.f, a1 = 0.f, a2 = 0.f, a3 = 0.f;
    #pragma unroll
    for (int kd = 0; kd < 3; ++kd) {
      const int dd = d - 1 + kd;
      if (dd < 0 || dd >= D) continue;
      const float* xd = xb + (long long)dd * HW;
      for (int cin = 0; cin < 16; ++cin) {
        const float* xc = xd + (long long)cin * DHW;
        const int wbase = cin * 27 + kd * 9;
        #pragma unroll
        for (int kh = 0; kh < 3; ++kh) {
          const int gh = h - 1 + kh;
          const bool vh = (gh >= 0) && (gh < H);
          #pragma unroll
          for (int kw = 0; kw < 3; ++kw) {
            const int gw = w - 1 + kw;
            float xv = (vh && gw >= 0 && gw < W) ? xc[gh * W + gw] : 0.f;
            const int wi = wbase + kh * 3 + kw;
            a0 = fmaf(xv, wg[wb0 + wi], a0);
            a1 = fmaf(xv, wg[wb1 + wi], a1);
            a2 = fmaf(xv, wg[wb2 + wi], a2);
            a3 = fmaf(xv, wg[wb3 + wi], a3);
          }
        }
      }
    }
    float Wx = tanhf(fmaf(a0, sc[0], bi[0]));
    float ft = 1.f / (1.f + __expf(-fmaf(a1, sc[1], bi[1])));
    float rt = 1.f / (1.f + __expf(-fmaf(a2, sc[2], bi[2])));
    float Xg = tanhf(fmaf(a3, sc[3], bi[3]));
    Ct = (d == 0) ? (1.f - ft) : fmaf(ft, Ct, (1.f - ft) * Wx);
    ob[(long long)d * HW] = fmaf(rt, Ct, (1.f - rt) * Xg);
  }
}

// ---------------------------------------------------------------------------
extern "C" void kernel_launch(void* const* d_in, const int* in_sizes, int n_in,
                              void* d_out, int out_size, void* d_ws, size_t ws_size,
                              hipStream_t stream) {
  const float* x      = (const float*)d_in[0];
  const float* w_pre  = (const float*)d_in[1];
  const float* bnpg   = (const float*)d_in[2];
  const float* bnpb   = (const float*)d_in[3];
  const float* bnpm   = (const float*)d_in[4];
  const float* bnpv   = (const float*)d_in[5];
  const float* wq     = (const float*)d_in[6];
  const float* wk     = (const float*)d_in[7];
  const float* wv     = (const float*)d_in[8];
  const float* gamma  = (const float*)d_in[9];
  const float* w_gate = (const float*)d_in[10];
  const float* bng    = (const float*)d_in[11];
  const float* bnb    = (const float*)d_in[12];
  const float* bnm    = (const float*)d_in[13];
  const float* bnv    = (const float*)d_in[14];

  float* ws  = (float*)d_ws;
  float* X1  = ws + OFF_X1;
  float* X2  = ws + OFF_X2;
  float* Q   = ws + OFF_Q;
  float* K   = ws + OFF_K;
  float* V   = ws + OFF_V;
  float* KT  = ws + OFF_KT;
  float* VT  = ws + OFF_VT;
  float* MST = ws + OFF_MST;
  float* out = (float*)d_out;

  // stage 1: conv_pre + BN + ReLU -> X1
  k_conv_pre<<<dim3(64, D, B), dim3(256), 0, stream>>>(x, w_pre, bnpg, bnpb, bnpm, bnpv, X1);

  // attention application 1: X1 -> X2
  k_qkv    <<<dim3(64, D, B), dim3(256), 0, stream>>>(X1, wq, wk, wv, Q, K, V, KT, VT);
  k_att_row<<<dim3(32, D, B), dim3(128), 0, stream>>>(X1, X2, Q, K, V, MST, gamma);
  k_att_col<<<dim3(32, D, B), dim3(128), 0, stream>>>(X2, Q, KT, VT, MST, gamma);

  // attention application 2: X2 -> X1
  k_qkv    <<<dim3(64, D, B), dim3(256), 0, stream>>>(X2, wq, wk, wv, Q, K, V, KT, VT);
  k_att_row<<<dim3(32, D, B), dim3(128), 0, stream>>>(X2, X1, Q, K, V, MST, gamma);
  k_att_col<<<dim3(32, D, B), dim3(128), 0, stream>>>(X1, Q, KT, VT, MST, gamma);

  // stage 3-5: conv_gate + BN + activations + SRU scan, fused -> out
  k_gate_scan<<<dim3(64, C, B), dim3(256), 0, stream>>>(X1, w_gate, bng, bnb, bnm, bnv, out);
}